// Round 10
// baseline (214.138 us; speedup 1.0000x reference)
//
#include <hip/hip_runtime.h>
#include <cstdint>
#include <cstddef>

typedef _Float16 half8  __attribute__((ext_vector_type(8)));
typedef float    f32x4  __attribute__((ext_vector_type(4)));

constexpr int Bc = 4, Tc = 4096, Hc = 16, NBc = 32, Dc = 1024, HIDc = 128;
constexpr int HN = Hc * NBc;      // 512
constexpr int BT = Bc * Tc;       // 16384

// ---------------------------------------------------------------------------
// split helper: 8 f32 -> f16 hi/lo (3-term split-f16 MFMA precision)
// ---------------------------------------------------------------------------
__device__ inline void split8(const float* __restrict__ p,
                              _Float16* __restrict__ dh,
                              _Float16* __restrict__ dl) {
  float4 a = *reinterpret_cast<const float4*>(p);
  float4 b = *reinterpret_cast<const float4*>(p + 4);
  float v[8] = {a.x, a.y, a.z, a.w, b.x, b.y, b.z, b.w};
  half8 hi, lo;
#pragma unroll
  for (int j = 0; j < 8; j++) {
    _Float16 h = (_Float16)v[j];
    hi[j] = h;
    lo[j] = (_Float16)(v[j] - (float)h);
  }
  *reinterpret_cast<half8*>(dh) = hi;
  *reinterpret_cast<half8*>(dl) = lo;
}

// ---------------------------------------------------------------------------
// Kernel: build transposed f16 hi/lo weights.
// ---------------------------------------------------------------------------
__global__ __launch_bounds__(256) void k_split_w(
    const float* __restrict__ mw1, const float* __restrict__ gw1,
    const float* __restrict__ mw2, const float* __restrict__ gw2,
    _Float16* __restrict__ W1Thi, _Float16* __restrict__ W1Tlo,
    _Float16* __restrict__ W2Thi, _Float16* __restrict__ W2Tlo) {
  unsigned i = blockIdx.x * 256u + threadIdx.x;
  if (i < 262144u) {                                   // W1T: n in [0,256), k in [0,1024)
    unsigned n = i >> 10, k = i & 1023u;
    float v = (n < 128u) ? mw1[k * 128u + n] : gw1[k * 128u + (n - 128u)];
    _Float16 h = (_Float16)v;
    W1Thi[i] = h;
    W1Tlo[i] = (_Float16)(v - (float)h);
  } else {                                             // W2T: j in [0,1024), k in [0,128)
    unsigned j2 = i - 262144u;
    unsigned n = j2 >> 7, k = j2 & 127u;
    float v = (n < 512u) ? mw2[k * 512u + n] : gw2[k * 512u + (n - 512u)];
    _Float16 h = (_Float16)v;
    W2Thi[j2] = h;
    W2Tlo[j2] = (_Float16)(v - (float)h);
  }
}

// ---------------------------------------------------------------------------
// GEMM1 v2: h[16384][256] = gelu(X @ [mw1|gw1] + [mb1|gb1]); split-f16 MFMA.
// Tile 64x256 (full col width), 4 waves, 256 blocks (1/CU): X read exactly
// once. Per-element accumulation order IDENTICAL to prior rounds (same kt
// sequence, same 3-term order) -> h bit-identical -> absmax preserved.
// ---------------------------------------------------------------------------
__global__ __launch_bounds__(256) void k_gemm1(
    const float* __restrict__ X,
    const _Float16* __restrict__ Whi, const _Float16* __restrict__ Wlo,
    const float* __restrict__ mb1, const float* __restrict__ gb1,
    _Float16* __restrict__ Hhi, _Float16* __restrict__ Hlo) {
  __shared__ _Float16 sAh[64][40],  sAl[64][40];    // 10 KB (+8 pad)
  __shared__ _Float16 sBh[256][40], sBl[256][40];   // 40 KB
  const int tid  = threadIdx.x;
  const int lane = tid & 63;
  const int wc   = tid >> 6;            // 0..3 (col 64-tile)
  const int rm   = blockIdx.x * 64;
  const int lr   = lane & 15, kg = (lane >> 4) * 8;

  f32x4 acc[4][4] = {};

  for (int kt = 0; kt < 1024; kt += 32) {
    // stage A: 64 rows x 32 k from f32 X (256 thr x 8 floats, exact cover)
    {
      int row = tid >> 2;
      int k0  = (tid & 3) * 8;
      size_t g = (size_t)(rm + row) * 1024 + kt + k0;
      split8(X + g, &sAh[row][k0], &sAl[row][k0]);
    }
    // stage B: 256 n x 32 k
#pragma unroll
    for (int j = 0; j < 4; j++) {
      int n  = j * 64 + (tid >> 2);
      int k0 = (tid & 3) * 8;
      size_t g = (size_t)n * 1024 + kt + k0;
      *reinterpret_cast<uint4*>(&sBh[n][k0]) = *reinterpret_cast<const uint4*>(Whi + g);
      *reinterpret_cast<uint4*>(&sBl[n][k0]) = *reinterpret_cast<const uint4*>(Wlo + g);
    }
    __syncthreads();

    half8 ah[4], al[4], bh[4], bl[4];
#pragma unroll
    for (int m = 0; m < 4; m++) {
      ah[m] = *reinterpret_cast<const half8*>(&sAh[m * 16 + lr][kg]);
      al[m] = *reinterpret_cast<const half8*>(&sAl[m * 16 + lr][kg]);
    }
#pragma unroll
    for (int n = 0; n < 4; n++) {
      bh[n] = *reinterpret_cast<const half8*>(&sBh[wc * 64 + n * 16 + lr][kg]);
      bl[n] = *reinterpret_cast<const half8*>(&sBl[wc * 64 + n * 16 + lr][kg]);
    }
#pragma unroll
    for (int m = 0; m < 4; m++)
#pragma unroll
      for (int n = 0; n < 4; n++) {
        acc[m][n] = __builtin_amdgcn_mfma_f32_16x16x32_f16(ah[m], bh[n], acc[m][n], 0, 0, 0);
        acc[m][n] = __builtin_amdgcn_mfma_f32_16x16x32_f16(ah[m], bl[n], acc[m][n], 0, 0, 0);
        acc[m][n] = __builtin_amdgcn_mfma_f32_16x16x32_f16(al[m], bh[n], acc[m][n], 0, 0, 0);
      }
    __syncthreads();
  }

#pragma unroll
  for (int n = 0; n < 4; n++) {
    int colg = wc * 64 + n * 16 + lr;
    float bias = (colg < 128) ? mb1[colg] : gb1[colg - 128];
#pragma unroll
    for (int m = 0; m < 4; m++) {
#pragma unroll
      for (int r = 0; r < 4; r++) {
        int rowg = rm + m * 16 + (lane >> 4) * 4 + r;
        float v  = acc[m][n][r] + bias;
        float ge = 0.5f * v * (1.0f + erff(v * 0.70710678118654752f));
        _Float16 h = (_Float16)ge;
        Hhi[(size_t)rowg * 256 + colg] = h;
        Hlo[(size_t)rowg * 256 + colg] = (_Float16)(ge - (float)h);
      }
    }
  }
}

// ---------------------------------------------------------------------------
// GEMM2 (R7 configuration): logits[16384][1024];
// cols<512: z = pi*tanh(.) -> zbuf; cols>=512: g = sigmoid(.) -> gout
// ---------------------------------------------------------------------------
__global__ __launch_bounds__(256) void k_gemm2(
    const _Float16* __restrict__ Hhi, const _Float16* __restrict__ Hlo,
    const _Float16* __restrict__ Whi, const _Float16* __restrict__ Wlo,
    const float* __restrict__ mb2, const float* __restrict__ gb2,
    float* __restrict__ zbuf, float* __restrict__ gout) {
  __shared__ _Float16 sAh[128][40], sAl[128][40];
  __shared__ _Float16 sBh[64][40],  sBl[64][40];
  const int tid  = threadIdx.x;
  const int lane = tid & 63;
  const int w    = tid >> 6;
  const int wr   = w >> 1, wc = w & 1;
  const int rm   = blockIdx.x * 128;
  const int cn   = blockIdx.y * 64;
  const int khead = (cn < 512) ? 0 : 128;
  const int lr   = lane & 15, kg = (lane >> 4) * 8;

  f32x4 acc[4][2] = {};

  for (int kt = 0; kt < 128; kt += 32) {
#pragma unroll
    for (int j = 0; j < 2; j++) {
      int row = j * 64 + (tid >> 2);
      int k0  = (tid & 3) * 8;
      size_t g = (size_t)(rm + row) * 256 + khead + kt + k0;
      *reinterpret_cast<uint4*>(&sAh[row][k0]) = *reinterpret_cast<const uint4*>(Hhi + g);
      *reinterpret_cast<uint4*>(&sAl[row][k0]) = *reinterpret_cast<const uint4*>(Hlo + g);
    }
    {
      int n  = tid >> 2;
      int k0 = (tid & 3) * 8;
      size_t g = (size_t)(cn + n) * 128 + kt + k0;
      *reinterpret_cast<uint4*>(&sBh[n][k0]) = *reinterpret_cast<const uint4*>(Whi + g);
      *reinterpret_cast<uint4*>(&sBl[n][k0]) = *reinterpret_cast<const uint4*>(Wlo + g);
    }
    __syncthreads();

    half8 ah[4], al[4], bh[2], bl[2];
#pragma unroll
    for (int m = 0; m < 4; m++) {
      ah[m] = *reinterpret_cast<const half8*>(&sAh[wr * 64 + m * 16 + lr][kg]);
      al[m] = *reinterpret_cast<const half8*>(&sAl[wr * 64 + m * 16 + lr][kg]);
    }
#pragma unroll
    for (int n = 0; n < 2; n++) {
      bh[n] = *reinterpret_cast<const half8*>(&sBh[wc * 32 + n * 16 + lr][kg]);
      bl[n] = *reinterpret_cast<const half8*>(&sBl[wc * 32 + n * 16 + lr][kg]);
    }
#pragma unroll
    for (int m = 0; m < 4; m++)
#pragma unroll
      for (int n = 0; n < 2; n++) {
        acc[m][n] = __builtin_amdgcn_mfma_f32_16x16x32_f16(ah[m], bh[n], acc[m][n], 0, 0, 0);
        acc[m][n] = __builtin_amdgcn_mfma_f32_16x16x32_f16(ah[m], bl[n], acc[m][n], 0, 0, 0);
        acc[m][n] = __builtin_amdgcn_mfma_f32_16x16x32_f16(al[m], bh[n], acc[m][n], 0, 0, 0);
      }
    __syncthreads();
  }

  const float PI = 3.14159265358979323846f;
#pragma unroll
  for (int n = 0; n < 2; n++) {
    int colg = cn + wc * 32 + n * 16 + lr;
    bool isz = (colg < 512);
    float bias = isz ? mb2[colg] : gb2[colg - 512];
#pragma unroll
    for (int m = 0; m < 4; m++) {
#pragma unroll
      for (int r = 0; r < 4; r++) {
        int rowg = rm + wr * 64 + m * 16 + (lane >> 4) * 4 + r;
        float v  = acc[m][n][r] + bias;
        if (isz) {
          zbuf[(size_t)rowg * 512 + colg] = PI * tanhf(v);
        } else {
          gout[(size_t)rowg * 512 + (colg - 512)] = 1.0f / (1.0f + expf(-v));
        }
      }
    }
  }
}

// ---------------------------------------------------------------------------
// Sigma recurrence as Mobius (LFT) parallel scan over T (R7 configuration).
// ---------------------------------------------------------------------------
__global__ __launch_bounds__(64) void k_mob1(
    const float* __restrict__ g, const float* __restrict__ logQ,
    const float* __restrict__ logR, float* __restrict__ Mbuf) {
  const int c  = blockIdx.x * 64 + threadIdx.x;   // channel 0..2047
  const int ts = blockIdx.y;                      // chunk 0..63
  const int b  = c >> 9, hn = c & 511;
  const float Q = expf(logQ[hn]);
  const float R = expf(logR[hn]);
  const unsigned base = (unsigned)b * (unsigned)(Tc * HN) + (unsigned)(ts * 64) * (unsigned)HN + (unsigned)hn;

  float ma = 1.f, mb = 0.f, mc = 0.f, md = 1.f;
  float gv[32];
#pragma unroll 1
  for (int ph = 0; ph < 2; ph++) {
#pragma unroll
    for (int j = 0; j < 32; j++) gv[j] = g[base + (unsigned)(ph * 32 + j) * 512u];
#pragma unroll
    for (int j = 0; j < 32; j++) {
      float re = R * __builtin_amdgcn_rcpf(gv[j] + 1e-4f);
      float t1 = __builtin_fmaf(Q, mc, ma);
      float t2 = __builtin_fmaf(Q, md, mb);
      ma = re * t1;
      mb = re * t2;
      mc = __builtin_fmaf(re, mc, t1);
      md = __builtin_fmaf(re, md, t2);
      if ((j & 3) == 3) {
        float r = __builtin_amdgcn_rcpf(md);
        ma *= r; mb *= r; mc *= r; md *= r;
      }
    }
  }
  f32x4 M; M[0] = ma; M[1] = mb; M[2] = mc; M[3] = md;
  reinterpret_cast<f32x4*>(Mbuf)[ts * 2048 + c] = M;
}

__global__ __launch_bounds__(64) void k_mob2(
    const float* __restrict__ Mbuf, const float* __restrict__ logS0,
    float* __restrict__ sstart) {
  const int c  = blockIdx.x * 64 + threadIdx.x;   // 0..2047
  const int hn = c & 511;
  float s = expf(logS0[hn]);
  const f32x4* M4 = reinterpret_cast<const f32x4*>(Mbuf);
  f32x4 ring[8];
#pragma unroll
  for (int i = 0; i < 8; i++) ring[i] = M4[i * 2048 + c];
#pragma unroll
  for (int ts = 0; ts < 64; ts++) {
    sstart[ts * 2048 + c] = s;
    f32x4 M = ring[ts & 7];
    if (ts + 8 < 64) ring[ts & 7] = M4[(ts + 8) * 2048 + c];
    s = (M[0] * s + M[1]) / (M[2] * s + M[3]);
  }
}

__global__ __launch_bounds__(64) void k_mob3(
    const float* __restrict__ g, const float* __restrict__ logQ,
    const float* __restrict__ logR, const float* __restrict__ sstart,
    float* __restrict__ Kbuf, float* __restrict__ osig) {
  const int c  = blockIdx.x * 64 + threadIdx.x;
  const int ts = blockIdx.y;
  const int b  = c >> 9, hn = c & 511;
  const float Q = expf(logQ[hn]);
  const float R = expf(logR[hn]);
  const unsigned base = (unsigned)b * (unsigned)(Tc * HN) + (unsigned)(ts * 64) * (unsigned)HN + (unsigned)hn;

  float s = sstart[ts * 2048 + c];
  float gv[32];
#pragma unroll 1
  for (int ph = 0; ph < 2; ph++) {
#pragma unroll
    for (int j = 0; j < 32; j++) gv[j] = g[base + (unsigned)(ph * 32 + j) * 512u];
#pragma unroll
    for (int j = 0; j < 32; j++) {
      const unsigned idx = base + (unsigned)(ph * 32 + j) * 512u;
      float re = R * __builtin_amdgcn_rcpf(gv[j] + 1e-4f);
      float sp = s + Q;
      float K  = sp * __builtin_amdgcn_rcpf(sp + re);
      s = K * re;
      Kbuf[idx] = K;        // Kbuf aliases out_theta ([b][t][hn] layout)
      osig[idx] = s;
    }
  }
}

// ---------------------------------------------------------------------------
// Serial theta scan v5 (R7 configuration) — VMEM-free compute wave,
// [tblk][ch] LDS layout, quarter-chunk register double-buffering.
// Theta arithmetic BIT-IDENTICAL to rounds 1-7 (absmax 0.0625 preserved).
// Alias (Karr==oth): K chunk m read at iter m-1; theta stored at iter m+1.
// ---------------------------------------------------------------------------
__global__ __launch_bounds__(448) void k_scan_theta(
    const float* __restrict__ tp, const float* __restrict__ zarr,
    const float* __restrict__ Karr, float* __restrict__ oth) {
  __shared__ float4 ibuf[2][3][16][64];   // 96 KB  [dbuf][stream][tblk][ch]
  __shared__ float4 obuf[2][16][64];      // 32 KB  [dbuf][tblk][ch]
  const int tid  = threadIdx.x;
  const int lane = tid & 63;
  const int wv   = tid >> 6;            // 0..6
  const int c    = blockIdx.x * 64 + lane;
  const int b    = c >> 9;
  const int hn   = c & 511;
  const unsigned base = (unsigned)b * (unsigned)(Tc * HN) + (unsigned)hn;

  constexpr float INV2PI = 0.15915494309189535f;
  constexpr float TWOPI  = 6.283185307179586f;

  // loader role (wave-uniform)
  const int s = (wv - 1) >> 1;          // 0:tp 1:z 2:K
  const int h = (wv - 1) & 1;           // half of the 64-step chunk
  const float* src = (s == 0) ? tp : (s == 1) ? zarr : Karr;

  float theta = 0.f, tprev = 0.f;

  auto load_chunk = [&](int k) {
    float r[32];
    const unsigned tb0 = (unsigned)(k * 64 + h * 32);
#pragma unroll
    for (int j = 0; j < 32; j++) r[j] = src[base + (tb0 + (unsigned)j) * 512u];
#pragma unroll
    for (int jj = 0; jj < 8; jj++) {
      float4 v; v.x = r[4*jj]; v.y = r[4*jj+1]; v.z = r[4*jj+2]; v.w = r[4*jj+3];
      ibuf[k & 1][s][h * 8 + jj][lane] = v;
    }
  };

  // prologue: load chunk 0 inputs
  if (wv >= 1) load_chunk(0);
  __syncthreads();

#pragma unroll 1
  for (int k = 0; k <= 64; k++) {
    if (wv == 0) {
      if (k < 64) {
        const int db = k & 1;
        float4 A[3][4], B[3][4];        // [stream][blk-in-quarter]

        auto LOADQ = [&](float4 (&dst)[3][4], int q) {
#pragma unroll
          for (int m2 = 0; m2 < 4; m2++)
#pragma unroll
            for (int st = 0; st < 3; st++)
              dst[st][m2] = ibuf[db][st][q * 4 + m2][lane];
        };
        auto COMPQ = [&](float4 (&sq)[3][4], int q) {
#pragma unroll
          for (int m2 = 0; m2 < 4; m2++) {
            float4 t4 = sq[0][m2], z4 = sq[1][m2], K4 = sq[2][m2];
            float4 th;
#pragma unroll
            for (int j = 0; j < 4; j++) {
              float tpv = (j == 0) ? t4.x : (j == 1) ? t4.y : (j == 2) ? t4.z : t4.w;
              float zv  = (j == 0) ? z4.x : (j == 1) ? z4.y : (j == 2) ? z4.z : z4.w;
              float Kv  = (j == 0) ? K4.x : (j == 1) ? K4.y : (j == 2) ? K4.z : K4.w;
              float inc = tpv - tprev; tprev = tpv;
              float thp = theta + inc;
              float d   = zv - thp;
              float nr  = rintf(d * INV2PI);
              float innov = __builtin_fmaf(-TWOPI, nr, d);
              theta = __builtin_fmaf(Kv, innov, thp);
              if (j == 0) th.x = theta; else if (j == 1) th.y = theta;
              else if (j == 2) th.z = theta; else th.w = theta;
            }
            obuf[db][q * 4 + m2][lane] = th;
          }
        };

        LOADQ(A, 0);
        LOADQ(B, 1); COMPQ(A, 0);
        LOADQ(A, 2); COMPQ(B, 1);
        LOADQ(B, 3); COMPQ(A, 2);
        COMPQ(B, 3);
      }
    } else {
      // flush chunk k-1 output: blocks tb = wv-1, wv-1+6, wv-1+12 (<16)
      if (k >= 1) {
        const unsigned tbase = (unsigned)((k - 1) * 64);
        const int fdb = (k - 1) & 1;
#pragma unroll
        for (int i = 0; i < 3; i++) {
          int tb = (wv - 1) + 6 * i;
          if (tb < 16) {
            float4 v = obuf[fdb][tb][lane];
            oth[base + (tbase + (unsigned)(4 * tb)    ) * 512u] = v.x;
            oth[base + (tbase + (unsigned)(4 * tb + 1)) * 512u] = v.y;
            oth[base + (tbase + (unsigned)(4 * tb + 2)) * 512u] = v.z;
            oth[base + (tbase + (unsigned)(4 * tb + 3)) * 512u] = v.w;
          }
        }
      }
      // prefetch chunk k+1 inputs
      if (k + 1 < 64) load_chunk(k + 1);
    }
    __syncthreads();
  }
}

// ---------------------------------------------------------------------------
extern "C" void kernel_launch(void* const* d_in, const int* in_sizes, int n_in,
                              void* d_out, int out_size, void* d_ws, size_t ws_size,
                              hipStream_t stream) {
  const float* theta_path = (const float*)d_in[0];
  const float* X     = (const float*)d_in[1];
  const float* mw1   = (const float*)d_in[2];
  const float* mb1   = (const float*)d_in[3];
  const float* mw2   = (const float*)d_in[4];
  const float* mb2   = (const float*)d_in[5];
  const float* gw1   = (const float*)d_in[6];
  const float* gb1   = (const float*)d_in[7];
  const float* gw2   = (const float*)d_in[8];
  const float* gb2   = (const float*)d_in[9];
  const float* logQ  = (const float*)d_in[10];
  const float* logR  = (const float*)d_in[11];
  const float* logS0 = (const float*)d_in[12];

  const size_t NOUT = (size_t)BT * HN;       // 8,388,608 per output tensor
  float* out_theta = (float*)d_out;
  float* out_sigma = out_theta + NOUT;
  float* out_g     = out_theta + 2 * NOUT;

  // K buffer aliases out_theta (identical [b][t][hn] layout); see scan notes.
  float* Kbuf = out_theta;

  char* ws = (char*)d_ws;
  _Float16* W1Thi = (_Float16*)(ws);                               // 512 KB
  _Float16* W1Tlo = (_Float16*)(ws + (512u << 10));                // 512 KB
  _Float16* W2Thi = (_Float16*)(ws + (1024u << 10));               // 256 KB
  _Float16* W2Tlo = (_Float16*)(ws + (1280u << 10));               // 256 KB
  _Float16* Hhi   = (_Float16*)(ws + (1536u << 10));               // 8 MB
  _Float16* Hlo   = (_Float16*)(ws + (1536u << 10) + (8u << 20));  // 8 MB
  float*    zbuf  = (float*)  (ws + (1536u << 10) + (16u << 20));  // 32 MB
  float*    Mbuf  = (float*)  (ws + (1536u << 10) + (48u << 20));  // 2 MB
  float*    sst   = (float*)  (ws + (1536u << 10) + (50u << 20));  // 512 KB
  // total ws use ~52 MB

  k_split_w<<<1536, 256, 0, stream>>>(mw1, gw1, mw2, gw2, W1Thi, W1Tlo, W2Thi, W2Tlo);
  k_gemm1<<<256, 256, 0, stream>>>(X, W1Thi, W1Tlo, mb1, gb1, Hhi, Hlo);
  k_gemm2<<<dim3(128, 16), 256, 0, stream>>>(Hhi, Hlo, W2Thi, W2Tlo, mb2, gb2, zbuf, out_g);
  k_mob1<<<dim3(32, 64), 64, 0, stream>>>(out_g, logQ, logR, Mbuf);
  k_mob2<<<32, 64, 0, stream>>>(Mbuf, logS0, sst);
  k_mob3<<<dim3(32, 64), 64, 0, stream>>>(out_g, logQ, logR, sst, Kbuf, out_sigma);
  k_scan_theta<<<32, 448, 0, stream>>>(theta_path, zbuf, Kbuf, out_theta);
}

// Round 11
// 193.664 us; speedup vs baseline: 1.1057x; 1.1057x over previous
//
#include <hip/hip_runtime.h>
#include <cstdint>
#include <cstddef>

typedef _Float16 half8  __attribute__((ext_vector_type(8)));
typedef float    f32x4  __attribute__((ext_vector_type(4)));

constexpr int Bc = 4, Tc = 4096, Hc = 16, NBc = 32, Dc = 1024, HIDc = 128;
constexpr int HN = Hc * NBc;      // 512
constexpr int BT = Bc * Tc;       // 16384

// ---------------------------------------------------------------------------
// split helper: 8 f32 -> f16 hi/lo (3-term split-f16 MFMA precision)
// ---------------------------------------------------------------------------
__device__ inline void split8(const float* __restrict__ p,
                              _Float16* __restrict__ dh,
                              _Float16* __restrict__ dl) {
  float4 a = *reinterpret_cast<const float4*>(p);
  float4 b = *reinterpret_cast<const float4*>(p + 4);
  float v[8] = {a.x, a.y, a.z, a.w, b.x, b.y, b.z, b.w};
  half8 hi, lo;
#pragma unroll
  for (int j = 0; j < 8; j++) {
    _Float16 h = (_Float16)v[j];
    hi[j] = h;
    lo[j] = (_Float16)(v[j] - (float)h);
  }
  *reinterpret_cast<half8*>(dh) = hi;
  *reinterpret_cast<half8*>(dl) = lo;
}

// ---------------------------------------------------------------------------
// Kernel: build transposed f16 hi/lo weights.
// ---------------------------------------------------------------------------
__global__ __launch_bounds__(256) void k_split_w(
    const float* __restrict__ mw1, const float* __restrict__ gw1,
    const float* __restrict__ mw2, const float* __restrict__ gw2,
    _Float16* __restrict__ W1Thi, _Float16* __restrict__ W1Tlo,
    _Float16* __restrict__ W2Thi, _Float16* __restrict__ W2Tlo) {
  unsigned i = blockIdx.x * 256u + threadIdx.x;
  if (i < 262144u) {                                   // W1T: n in [0,256), k in [0,1024)
    unsigned n = i >> 10, k = i & 1023u;
    float v = (n < 128u) ? mw1[k * 128u + n] : gw1[k * 128u + (n - 128u)];
    _Float16 h = (_Float16)v;
    W1Thi[i] = h;
    W1Tlo[i] = (_Float16)(v - (float)h);
  } else {                                             // W2T: j in [0,1024), k in [0,128)
    unsigned j2 = i - 262144u;
    unsigned n = j2 >> 7, k = j2 & 127u;
    float v = (n < 512u) ? mw2[k * 512u + n] : gw2[k * 512u + (n - 512u)];
    _Float16 h = (_Float16)v;
    W2Thi[j2] = h;
    W2Tlo[j2] = (_Float16)(v - (float)h);
  }
}

// ---------------------------------------------------------------------------
// GEMM1 (R7 configuration): h[16384][256] = gelu(X @ [mw1|gw1] + [mb1|gb1]).
// ---------------------------------------------------------------------------
__global__ __launch_bounds__(256) void k_gemm1(
    const float* __restrict__ X,
    const _Float16* __restrict__ Whi, const _Float16* __restrict__ Wlo,
    const float* __restrict__ mb1, const float* __restrict__ gb1,
    _Float16* __restrict__ Hhi, _Float16* __restrict__ Hlo) {
  __shared__ _Float16 sAh[128][40], sAl[128][40];   // +8 pad: 80B row stride
  __shared__ _Float16 sBh[64][40],  sBl[64][40];
  const int tid  = threadIdx.x;
  const int lane = tid & 63;
  const int w    = tid >> 6;
  const int wr   = w >> 1, wc = w & 1;
  const int rm   = blockIdx.x * 128;
  const int cn   = blockIdx.y * 64;
  const int lr   = lane & 15, kg = (lane >> 4) * 8;

  f32x4 acc[4][2] = {};

  for (int kt = 0; kt < 1024; kt += 32) {
#pragma unroll
    for (int j = 0; j < 2; j++) {
      int row = j * 64 + (tid >> 2);
      int k0  = (tid & 3) * 8;
      size_t g = (size_t)(rm + row) * 1024 + kt + k0;
      split8(X + g, &sAh[row][k0], &sAl[row][k0]);
    }
    {
      int n  = tid >> 2;
      int k0 = (tid & 3) * 8;
      size_t g = (size_t)(cn + n) * 1024 + kt + k0;
      *reinterpret_cast<uint4*>(&sBh[n][k0]) = *reinterpret_cast<const uint4*>(Whi + g);
      *reinterpret_cast<uint4*>(&sBl[n][k0]) = *reinterpret_cast<const uint4*>(Wlo + g);
    }
    __syncthreads();

    half8 ah[4], al[4], bh[2], bl[2];
#pragma unroll
    for (int m = 0; m < 4; m++) {
      ah[m] = *reinterpret_cast<const half8*>(&sAh[wr * 64 + m * 16 + lr][kg]);
      al[m] = *reinterpret_cast<const half8*>(&sAl[wr * 64 + m * 16 + lr][kg]);
    }
#pragma unroll
    for (int n = 0; n < 2; n++) {
      bh[n] = *reinterpret_cast<const half8*>(&sBh[wc * 32 + n * 16 + lr][kg]);
      bl[n] = *reinterpret_cast<const half8*>(&sBl[wc * 32 + n * 16 + lr][kg]);
    }
#pragma unroll
    for (int m = 0; m < 4; m++)
#pragma unroll
      for (int n = 0; n < 2; n++) {
        acc[m][n] = __builtin_amdgcn_mfma_f32_16x16x32_f16(ah[m], bh[n], acc[m][n], 0, 0, 0);
        acc[m][n] = __builtin_amdgcn_mfma_f32_16x16x32_f16(ah[m], bl[n], acc[m][n], 0, 0, 0);
        acc[m][n] = __builtin_amdgcn_mfma_f32_16x16x32_f16(al[m], bh[n], acc[m][n], 0, 0, 0);
      }
    __syncthreads();
  }

#pragma unroll
  for (int n = 0; n < 2; n++) {
    int colg = cn + wc * 32 + n * 16 + lr;
    float bias = (colg < 128) ? mb1[colg] : gb1[colg - 128];
#pragma unroll
    for (int m = 0; m < 4; m++) {
#pragma unroll
      for (int r = 0; r < 4; r++) {
        int rowg = rm + wr * 64 + m * 16 + (lane >> 4) * 4 + r;
        float v  = acc[m][n][r] + bias;
        float ge = 0.5f * v * (1.0f + erff(v * 0.70710678118654752f));
        _Float16 h = (_Float16)ge;
        Hhi[(size_t)rowg * 256 + colg] = h;
        Hlo[(size_t)rowg * 256 + colg] = (_Float16)(ge - (float)h);
      }
    }
  }
}

// ---------------------------------------------------------------------------
// GEMM2 (R7 configuration): logits[16384][1024];
// cols<512: z = pi*tanh(.) -> zbuf; cols>=512: g = sigmoid(.) -> gout
// ---------------------------------------------------------------------------
__global__ __launch_bounds__(256) void k_gemm2(
    const _Float16* __restrict__ Hhi, const _Float16* __restrict__ Hlo,
    const _Float16* __restrict__ Whi, const _Float16* __restrict__ Wlo,
    const float* __restrict__ mb2, const float* __restrict__ gb2,
    float* __restrict__ zbuf, float* __restrict__ gout) {
  __shared__ _Float16 sAh[128][40], sAl[128][40];
  __shared__ _Float16 sBh[64][40],  sBl[64][40];
  const int tid  = threadIdx.x;
  const int lane = tid & 63;
  const int w    = tid >> 6;
  const int wr   = w >> 1, wc = w & 1;
  const int rm   = blockIdx.x * 128;
  const int cn   = blockIdx.y * 64;
  const int khead = (cn < 512) ? 0 : 128;
  const int lr   = lane & 15, kg = (lane >> 4) * 8;

  f32x4 acc[4][2] = {};

  for (int kt = 0; kt < 128; kt += 32) {
#pragma unroll
    for (int j = 0; j < 2; j++) {
      int row = j * 64 + (tid >> 2);
      int k0  = (tid & 3) * 8;
      size_t g = (size_t)(rm + row) * 256 + khead + kt + k0;
      *reinterpret_cast<uint4*>(&sAh[row][k0]) = *reinterpret_cast<const uint4*>(Hhi + g);
      *reinterpret_cast<uint4*>(&sAl[row][k0]) = *reinterpret_cast<const uint4*>(Hlo + g);
    }
    {
      int n  = tid >> 2;
      int k0 = (tid & 3) * 8;
      size_t g = (size_t)(cn + n) * 128 + kt + k0;
      *reinterpret_cast<uint4*>(&sBh[n][k0]) = *reinterpret_cast<const uint4*>(Whi + g);
      *reinterpret_cast<uint4*>(&sBl[n][k0]) = *reinterpret_cast<const uint4*>(Wlo + g);
    }
    __syncthreads();

    half8 ah[4], al[4], bh[2], bl[2];
#pragma unroll
    for (int m = 0; m < 4; m++) {
      ah[m] = *reinterpret_cast<const half8*>(&sAh[wr * 64 + m * 16 + lr][kg]);
      al[m] = *reinterpret_cast<const half8*>(&sAl[wr * 64 + m * 16 + lr][kg]);
    }
#pragma unroll
    for (int n = 0; n < 2; n++) {
      bh[n] = *reinterpret_cast<const half8*>(&sBh[wc * 32 + n * 16 + lr][kg]);
      bl[n] = *reinterpret_cast<const half8*>(&sBl[wc * 32 + n * 16 + lr][kg]);
    }
#pragma unroll
    for (int m = 0; m < 4; m++)
#pragma unroll
      for (int n = 0; n < 2; n++) {
        acc[m][n] = __builtin_amdgcn_mfma_f32_16x16x32_f16(ah[m], bh[n], acc[m][n], 0, 0, 0);
        acc[m][n] = __builtin_amdgcn_mfma_f32_16x16x32_f16(ah[m], bl[n], acc[m][n], 0, 0, 0);
        acc[m][n] = __builtin_amdgcn_mfma_f32_16x16x32_f16(al[m], bh[n], acc[m][n], 0, 0, 0);
      }
    __syncthreads();
  }

  const float PI = 3.14159265358979323846f;
#pragma unroll
  for (int n = 0; n < 2; n++) {
    int colg = cn + wc * 32 + n * 16 + lr;
    bool isz = (colg < 512);
    float bias = isz ? mb2[colg] : gb2[colg - 512];
#pragma unroll
    for (int m = 0; m < 4; m++) {
#pragma unroll
      for (int r = 0; r < 4; r++) {
        int rowg = rm + wr * 64 + m * 16 + (lane >> 4) * 4 + r;
        float v  = acc[m][n][r] + bias;
        if (isz) {
          zbuf[(size_t)rowg * 512 + colg] = PI * tanhf(v);
        } else {
          gout[(size_t)rowg * 512 + (colg - 512)] = 1.0f / (1.0f + expf(-v));
        }
      }
    }
  }
}

// ---------------------------------------------------------------------------
// Sigma recurrence as Mobius (LFT) parallel scan over T (R7 configuration).
// ---------------------------------------------------------------------------
__global__ __launch_bounds__(64) void k_mob1(
    const float* __restrict__ g, const float* __restrict__ logQ,
    const float* __restrict__ logR, float* __restrict__ Mbuf) {
  const int c  = blockIdx.x * 64 + threadIdx.x;   // channel 0..2047
  const int ts = blockIdx.y;                      // chunk 0..63
  const int b  = c >> 9, hn = c & 511;
  const float Q = expf(logQ[hn]);
  const float R = expf(logR[hn]);
  const unsigned base = (unsigned)b * (unsigned)(Tc * HN) + (unsigned)(ts * 64) * (unsigned)HN + (unsigned)hn;

  float ma = 1.f, mb = 0.f, mc = 0.f, md = 1.f;
  float gv[32];
#pragma unroll 1
  for (int ph = 0; ph < 2; ph++) {
#pragma unroll
    for (int j = 0; j < 32; j++) gv[j] = g[base + (unsigned)(ph * 32 + j) * 512u];
#pragma unroll
    for (int j = 0; j < 32; j++) {
      float re = R * __builtin_amdgcn_rcpf(gv[j] + 1e-4f);
      float t1 = __builtin_fmaf(Q, mc, ma);
      float t2 = __builtin_fmaf(Q, md, mb);
      ma = re * t1;
      mb = re * t2;
      mc = __builtin_fmaf(re, mc, t1);
      md = __builtin_fmaf(re, md, t2);
      if ((j & 3) == 3) {
        float r = __builtin_amdgcn_rcpf(md);
        ma *= r; mb *= r; mc *= r; md *= r;
      }
    }
  }
  f32x4 M; M[0] = ma; M[1] = mb; M[2] = mc; M[3] = md;
  reinterpret_cast<f32x4*>(Mbuf)[ts * 2048 + c] = M;
}

__global__ __launch_bounds__(64) void k_mob2(
    const float* __restrict__ Mbuf, const float* __restrict__ logS0,
    float* __restrict__ sstart) {
  const int c  = blockIdx.x * 64 + threadIdx.x;   // 0..2047
  const int hn = c & 511;
  float s = expf(logS0[hn]);
  const f32x4* M4 = reinterpret_cast<const f32x4*>(Mbuf);
  f32x4 ring[8];
#pragma unroll
  for (int i = 0; i < 8; i++) ring[i] = M4[i * 2048 + c];
#pragma unroll
  for (int ts = 0; ts < 64; ts++) {
    sstart[ts * 2048 + c] = s;
    f32x4 M = ring[ts & 7];
    if (ts + 8 < 64) ring[ts & 7] = M4[(ts + 8) * 2048 + c];
    s = (M[0] * s + M[1]) / (M[2] * s + M[3]);
  }
}

__global__ __launch_bounds__(64) void k_mob3(
    const float* __restrict__ g, const float* __restrict__ logQ,
    const float* __restrict__ logR, const float* __restrict__ sstart,
    float* __restrict__ Kbuf, float* __restrict__ osig) {
  const int c  = blockIdx.x * 64 + threadIdx.x;
  const int ts = blockIdx.y;
  const int b  = c >> 9, hn = c & 511;
  const float Q = expf(logQ[hn]);
  const float R = expf(logR[hn]);
  const unsigned base = (unsigned)b * (unsigned)(Tc * HN) + (unsigned)(ts * 64) * (unsigned)HN + (unsigned)hn;

  float s = sstart[ts * 2048 + c];
  float gv[32];
#pragma unroll 1
  for (int ph = 0; ph < 2; ph++) {
#pragma unroll
    for (int j = 0; j < 32; j++) gv[j] = g[base + (unsigned)(ph * 32 + j) * 512u];
#pragma unroll
    for (int j = 0; j < 32; j++) {
      const unsigned idx = base + (unsigned)(ph * 32 + j) * 512u;
      float re = R * __builtin_amdgcn_rcpf(gv[j] + 1e-4f);
      float sp = s + Q;
      float K  = sp * __builtin_amdgcn_rcpf(sp + re);
      s = K * re;
      Kbuf[idx] = K;        // Kbuf aliases out_theta ([b][t][hn] layout)
      osig[idx] = s;
    }
  }
}

// ---------------------------------------------------------------------------
// Serial theta scan v5 + T5 (R7 configuration + wave0 s_setprio(1)).
// VMEM-free compute wave, [tblk][ch] LDS layout, quarter-chunk register
// double-buffering. Wave0 runs at elevated priority so loader-wave issue
// bursts on the same SIMD don't displace its dependent FP chain.
// Theta arithmetic BIT-IDENTICAL to rounds 1-7 (absmax 0.0625 preserved).
// Alias (Karr==oth): K chunk m read at iter m-1; theta stored at iter m+1.
// ---------------------------------------------------------------------------
__global__ __launch_bounds__(448) void k_scan_theta(
    const float* __restrict__ tp, const float* __restrict__ zarr,
    const float* __restrict__ Karr, float* __restrict__ oth) {
  __shared__ float4 ibuf[2][3][16][64];   // 96 KB  [dbuf][stream][tblk][ch]
  __shared__ float4 obuf[2][16][64];      // 32 KB  [dbuf][tblk][ch]
  const int tid  = threadIdx.x;
  const int lane = tid & 63;
  const int wv   = tid >> 6;            // 0..6
  const int c    = blockIdx.x * 64 + lane;
  const int b    = c >> 9;
  const int hn   = c & 511;
  const unsigned base = (unsigned)b * (unsigned)(Tc * HN) + (unsigned)hn;

  constexpr float INV2PI = 0.15915494309189535f;
  constexpr float TWOPI  = 6.283185307179586f;

  // loader role (wave-uniform)
  const int s = (wv - 1) >> 1;          // 0:tp 1:z 2:K
  const int h = (wv - 1) & 1;           // half of the 64-step chunk
  const float* src = (s == 0) ? tp : (s == 1) ? zarr : Karr;

  float theta = 0.f, tprev = 0.f;

  auto load_chunk = [&](int k) {
    float r[32];
    const unsigned tb0 = (unsigned)(k * 64 + h * 32);
#pragma unroll
    for (int j = 0; j < 32; j++) r[j] = src[base + (tb0 + (unsigned)j) * 512u];
#pragma unroll
    for (int jj = 0; jj < 8; jj++) {
      float4 v; v.x = r[4*jj]; v.y = r[4*jj+1]; v.z = r[4*jj+2]; v.w = r[4*jj+3];
      ibuf[k & 1][s][h * 8 + jj][lane] = v;
    }
  };

  // prologue: load chunk 0 inputs
  if (wv >= 1) load_chunk(0);
  __syncthreads();

  if (wv == 0) __builtin_amdgcn_s_setprio(1);   // T5: favor the serial chain

#pragma unroll 1
  for (int k = 0; k <= 64; k++) {
    if (wv == 0) {
      if (k < 64) {
        const int db = k & 1;
        float4 A[3][4], B[3][4];        // [stream][blk-in-quarter]

        auto LOADQ = [&](float4 (&dst)[3][4], int q) {
#pragma unroll
          for (int m2 = 0; m2 < 4; m2++)
#pragma unroll
            for (int st = 0; st < 3; st++)
              dst[st][m2] = ibuf[db][st][q * 4 + m2][lane];
        };
        auto COMPQ = [&](float4 (&sq)[3][4], int q) {
#pragma unroll
          for (int m2 = 0; m2 < 4; m2++) {
            float4 t4 = sq[0][m2], z4 = sq[1][m2], K4 = sq[2][m2];
            float4 th;
#pragma unroll
            for (int j = 0; j < 4; j++) {
              float tpv = (j == 0) ? t4.x : (j == 1) ? t4.y : (j == 2) ? t4.z : t4.w;
              float zv  = (j == 0) ? z4.x : (j == 1) ? z4.y : (j == 2) ? z4.z : z4.w;
              float Kv  = (j == 0) ? K4.x : (j == 1) ? K4.y : (j == 2) ? K4.z : K4.w;
              float inc = tpv - tprev; tprev = tpv;
              float thp = theta + inc;
              float d   = zv - thp;
              float nr  = rintf(d * INV2PI);
              float innov = __builtin_fmaf(-TWOPI, nr, d);
              theta = __builtin_fmaf(Kv, innov, thp);
              if (j == 0) th.x = theta; else if (j == 1) th.y = theta;
              else if (j == 2) th.z = theta; else th.w = theta;
            }
            obuf[db][q * 4 + m2][lane] = th;
          }
        };

        LOADQ(A, 0);
        LOADQ(B, 1); COMPQ(A, 0);
        LOADQ(A, 2); COMPQ(B, 1);
        LOADQ(B, 3); COMPQ(A, 2);
        COMPQ(B, 3);
      }
    } else {
      // flush chunk k-1 output: blocks tb = wv-1, wv-1+6, wv-1+12 (<16)
      if (k >= 1) {
        const unsigned tbase = (unsigned)((k - 1) * 64);
        const int fdb = (k - 1) & 1;
#pragma unroll
        for (int i = 0; i < 3; i++) {
          int tb = (wv - 1) + 6 * i;
          if (tb < 16) {
            float4 v = obuf[fdb][tb][lane];
            oth[base + (tbase + (unsigned)(4 * tb)    ) * 512u] = v.x;
            oth[base + (tbase + (unsigned)(4 * tb + 1)) * 512u] = v.y;
            oth[base + (tbase + (unsigned)(4 * tb + 2)) * 512u] = v.z;
            oth[base + (tbase + (unsigned)(4 * tb + 3)) * 512u] = v.w;
          }
        }
      }
      // prefetch chunk k+1 inputs
      if (k + 1 < 64) load_chunk(k + 1);
    }
    __syncthreads();
  }
}

// ---------------------------------------------------------------------------
extern "C" void kernel_launch(void* const* d_in, const int* in_sizes, int n_in,
                              void* d_out, int out_size, void* d_ws, size_t ws_size,
                              hipStream_t stream) {
  const float* theta_path = (const float*)d_in[0];
  const float* X     = (const float*)d_in[1];
  const float* mw1   = (const float*)d_in[2];
  const float* mb1   = (const float*)d_in[3];
  const float* mw2   = (const float*)d_in[4];
  const float* mb2   = (const float*)d_in[5];
  const float* gw1   = (const float*)d_in[6];
  const float* gb1   = (const float*)d_in[7];
  const float* gw2   = (const float*)d_in[8];
  const float* gb2   = (const float*)d_in[9];
  const float* logQ  = (const float*)d_in[10];
  const float* logR  = (const float*)d_in[11];
  const float* logS0 = (const float*)d_in[12];

  const size_t NOUT = (size_t)BT * HN;       // 8,388,608 per output tensor
  float* out_theta = (float*)d_out;
  float* out_sigma = out_theta + NOUT;
  float* out_g     = out_theta + 2 * NOUT;

  // K buffer aliases out_theta (identical [b][t][hn] layout); see scan notes.
  float* Kbuf = out_theta;

  char* ws = (char*)d_ws;
  _Float16* W1Thi = (_Float16*)(ws);                               // 512 KB
  _Float16* W1Tlo = (_Float16*)(ws + (512u << 10));                // 512 KB
  _Float16* W2Thi = (_Float16*)(ws + (1024u << 10));               // 256 KB
  _Float16* W2Tlo = (_Float16*)(ws + (1280u << 10));               // 256 KB
  _Float16* Hhi   = (_Float16*)(ws + (1536u << 10));               // 8 MB
  _Float16* Hlo   = (_Float16*)(ws + (1536u << 10) + (8u << 20));  // 8 MB
  float*    zbuf  = (float*)  (ws + (1536u << 10) + (16u << 20));  // 32 MB
  float*    Mbuf  = (float*)  (ws + (1536u << 10) + (48u << 20));  // 2 MB
  float*    sst   = (float*)  (ws + (1536u << 10) + (50u << 20));  // 512 KB
  // total ws use ~52 MB

  k_split_w<<<1536, 256, 0, stream>>>(mw1, gw1, mw2, gw2, W1Thi, W1Tlo, W2Thi, W2Tlo);
  k_gemm1<<<dim3(128, 4), 256, 0, stream>>>(X, W1Thi, W1Tlo, mb1, gb1, Hhi, Hlo);
  k_gemm2<<<dim3(128, 16), 256, 0, stream>>>(Hhi, Hlo, W2Thi, W2Tlo, mb2, gb2, zbuf, out_g);
  k_mob1<<<dim3(32, 64), 64, 0, stream>>>(out_g, logQ, logR, Mbuf);
  k_mob2<<<32, 64, 0, stream>>>(Mbuf, logS0, sst);
  k_mob3<<<dim3(32, 64), 64, 0, stream>>>(out_g, logQ, logR, sst, Kbuf, out_sigma);
  k_scan_theta<<<32, 448, 0, stream>>>(theta_path, zbuf, Kbuf, out_theta);
}